// Round 3
// baseline (2191.912 us; speedup 1.0000x reference)
//
#include <hip/hip_runtime.h>
#include <hip/hip_cooperative_groups.h>

namespace cg = cooperative_groups;

#define DEV __device__ __forceinline__
#define NSLOT 64   // slot rows == 64 lanes -> lane-parallel fold

// ---- quantizer helpers (exact, round-half-even matches jnp.round) ----
DEV float qwt(float w) {
    float y = fminf(fmaxf(w, -1.0f), 0.875f);
    return rintf(y * 8.0f) * 0.125f;
}
DEV int qw8i(float w) {                       // weight -> int in [-8,7]
    float y = fminf(fmaxf(w, -1.0f), 0.875f);
    return (int)rintf(y * 8.0f);
}
DEV int q8i(float x, float a, float b) {      // act -> int in [-8,7]
    float y = fmaf(x, a, b);
    y = fminf(fmaxf(y, -1.0f), 0.875f);
    return (int)rintf(y * 8.0f);
}
DEV float qact(float x, float a, float b) {
    float y = fmaf(x, a, b);
    y = fminf(fmaxf(y, -1.0f), 0.875f);
    return rintf(y * 8.0f) * 0.125f;
}

DEV int dot4(int a, int b, int c) {
#if __has_builtin(__builtin_amdgcn_sdot4)
    return __builtin_amdgcn_sdot4(a, b, c, false);
#else
    c += (int)(signed char)(a)       * (int)(signed char)(b);
    c += (int)(signed char)(a >> 8)  * (int)(signed char)(b >> 8);
    c += (int)(signed char)(a >> 16) * (int)(signed char)(b >> 16);
    c += (int)(signed char)(a >> 24) * (int)(signed char)(b >> 24);
    return c;
#endif
}
DEV unsigned alignpair(unsigned hi, unsigned lo, int bits) {
#if __has_builtin(__builtin_amdgcn_alignbit)
    return __builtin_amdgcn_alignbit(hi, lo, bits);
#else
    return bits ? ((lo >> bits) | (hi << (32 - bits))) : lo;
#endif
}
DEV double shfl_down_d(double v, int off) {
    int lo = __shfl_down(__double2loint(v), off, 64);
    int hi = __shfl_down(__double2hiint(v), off, 64);
    return __hiloint2double(hi, lo);
}

// pack float OIHW weights -> int8x4 dwords (value*8), zero-padded past K
DEV void pack_layer(const float* w, int* o, int CIN, int COUT, int K, int t) {
    int KW = (K + 3) / 4;
    for (int i = t; i < COUT * CIN * KW; i += 256) {
        int j = i % KW, cc = i / KW;
        unsigned r = 0;
        for (int u = 0; u < 4; u++) {
            int k = 4 * j + u;
            int b = (k < K) ? (qw8i(w[cc * K + k]) & 0xff) : 0;
            r |= (unsigned)b << (8 * u);
        }
        o[i] = (int)r;
    }
}

// ---------------------------------------------------------------------------
struct Params {
    const float *x, *w1, *w2, *w3, *w4, *w5, *fw1, *fw2;
    const float *g1, *b1, *g2, *b2, *g3, *b3, *g4, *b4, *g5, *b5, *g6, *b6, *g7, *b7;
    short *y1, *y2, *y3, *y4, *y5;
    float *z1, *z2;
    int *wp2, *wp3, *wp4, *wp5;
    double *sl1, *sl2, *sl3, *sl4, *sl5, *sl6, *sl7;
    float *outp;
};

// ---------------------------------------------------------------------------
// LDS layout within the 30720-B shared block (SB):
//   conv phases: smem @0 (<=12832+pad), ts @13056, tb @13184, red @13312
//                (4 x 2*COUT floats, <=640B), lwq @13984 (conv1 only)
//   fc1:         wq @0 (29600B), ts @29600, tb @29696, red @29792 (320B)
//   fc2:         ts7 @0, tb7 @64, wq2 @128, frd(double) @256, tr @512
// ---------------------------------------------------------------------------

// int8/dot4 1-D strided conv phase (stride 2, VALID). Virtual-block loop
// strided by gridDim.x; per-vb stat grouping + slot index (vb&63) are
// grid-size-invariant, so the f64 slot sums (exact sums of f32 partials)
// match the multi-kernel version bit-for-bit.
template<int CIN,int COUT,int K,int LINP,int LOUT,int LOUTP,int P,int R,bool IN_FLOAT,int LIN>
DEV void conv_phase(char* SB,
    const void* __restrict__ in_, const int* __restrict__ wqi,
    const double* __restrict__ statsIn,
    const float* __restrict__ gprev, const float* __restrict__ bprev, double Nprev,
    short* __restrict__ out, double* __restrict__ statsOut, int B, int VB,
    const float* __restrict__ wown,
    const float* __restrict__ pw2, const float* __restrict__ pw3,
    const float* __restrict__ pw4, const float* __restrict__ pw5,
    int* __restrict__ owp2, int* __restrict__ owp3,
    int* __restrict__ owp4, int* __restrict__ owp5)
{
    constexpr int KW   = (K + 3) / 4;
    constexpr int NE   = P + 2 * KW - 1;
    constexpr int ND   = (2 * (NE - 1) + 3) / 4 + 2;
    constexpr int LO_P = (LOUT + P - 1) / P;
    constexpr int GROUPS = R * LO_P;

    signed char* smem = (signed char*)SB;
    float* ts  = (float*)(SB + 13056);
    float* tb  = (float*)(SB + 13184);
    float* red = (float*)(SB + 13312);     // [4][2*COUT]
    int*   lwq = (int*)  (SB + 13984);

    const int tid  = threadIdx.x;
    const int bid  = blockIdx.x;
    const int lane = tid & 63, wid = tid >> 6;

    if constexpr (IN_FLOAT) {
        for (int i = tid; i < COUT * CIN * KW; i += 256) {
            int j = i % KW, cc = i / KW;
            unsigned rr = 0;
            for (int u = 0; u < 4; u++) {
                int k = 4 * j + u;
                int bv = (k < K) ? (qw8i(wown[cc * K + k]) & 0xff) : 0;
                rr |= (unsigned)bv << (8 * u);
            }
            lwq[i] = (int)rr;
        }
        if (bid == 0) {
            pack_layer(pw2, owp2, 3, 5, 5, tid);
            pack_layer(pw3, owp3, 5, 10, 4, tid);
            pack_layer(pw4, owp4, 10, 20, 4, tid);
            pack_layer(pw5, owp5, 20, 20, 4, tid);
        }
    } else {
        // lane-parallel slot fold: lane l owns slot row l (NSLOT==64)
        for (int c = wid; c < CIN; c += 4) {
            double S = statsIn[lane * (2 * CIN) + 2 * c];
            double Q = statsIn[lane * (2 * CIN) + 2 * c + 1];
            for (int off = 32; off > 0; off >>= 1) {
                S += shfl_down_d(S, off);
                Q += shfl_down_d(Q, off);
            }
            if (lane == 0) {
                double mean = S / Nprev;
                double var  = Q / Nprev - mean * mean;
                double inv  = 1.0 / sqrt(var + 1e-5);
                double sc   = (double)gprev[c] * inv;
                ts[c] = (float)sc * 0.015625f;   // fold /64 of int16 storage
                tb[c] = (float)((double)bprev[c] - mean * sc);
            }
        }
    }
    __syncthreads();

#pragma unroll 1
    for (int vb = bid; vb < VB; vb += gridDim.x) {
        const int r0   = vb * R;
        const int rcnt = min(R, B - r0);

        // ---- stage: global -> quantized int8 LDS ----
        if constexpr (IN_FLOAT) {
            constexpr int CH = LIN / 2;
            const float2* gp = (const float2*)in_;
            for (int c = tid; c < rcnt * CH; c += 256) {
                int r = c / CH, rem = c - r * CH;
                float2 v = gp[(size_t)(r0 + r) * CH + rem];
                int b0 = q8i(v.x, 1.f, 0.f) & 0xff;
                int b1 = q8i(v.y, 1.f, 0.f) & 0xff;
                *(unsigned short*)(smem + r * LINP + rem * 2) =
                    (unsigned short)(b0 | (b1 << 8));
            }
        } else {
            constexpr int CH  = CIN * LINP / 8;
            constexpr int CHC = LINP / 8;
            const int4* gp = (const int4*)((const short*)in_ + (size_t)r0 * CIN * LINP);
            for (int c = tid; c < rcnt * CH; c += 256) {
                int rem = c % CH;
                int ci = rem / CHC;
                float a = ts[ci], bo = tb[ci];
                int4 v = gp[c];
                int vs[4] = { v.x, v.y, v.z, v.w };
                unsigned pk[2];
#pragma unroll
                for (int u = 0; u < 2; u++) {
                    unsigned pp = 0;
#pragma unroll
                    for (int j = 0; j < 2; j++) {
                        int word = vs[u * 2 + j];
                        int b0 = q8i((float)(short)(word & 0xffff), a, bo) & 0xff;
                        int b1 = q8i((float)(short)(word >> 16),    a, bo) & 0xff;
                        pp |= (unsigned)(b0 | (b1 << 8)) << (16 * j);
                    }
                    pk[u] = pp;
                }
                ((uint2*)smem)[c] = make_uint2(pk[0], pk[1]);
            }
        }
        __syncthreads();

        float tsum[COUT], tsq[COUT];
#pragma unroll
        for (int c = 0; c < COUT; c++) { tsum[c] = 0.f; tsq[c] = 0.f; }

        // ---- compute core (verbatim) ----
#pragma unroll 1
        for (int g = tid; g < GROUPS; g += 256) {
            int r = g / LO_P;
            if (r >= rcnt) continue;
            int l0   = (g - r * LO_P) * P;
            int pact = min(P, LOUT - l0);

            int acc[COUT][P];
#pragma unroll
            for (int co = 0; co < COUT; co++)
#pragma unroll
                for (int p = 0; p < P; p++) acc[co][p] = 0;

            const int ibase = r * CIN * LINP + 2 * l0;
            const int sh    = (P % 2 == 0) ? 0 : (ibase & 3);

            for (int ci = 0; ci < CIN; ci++) {
                const int* sp = (const int*)smem + ((ci * LINP + (ibase & ~3)) >> 2);
                int d[ND];
#pragma unroll
                for (int j = 0; j < ND; j++) d[j] = sp[j];
                int e[NE];
#pragma unroll
                for (int i = 0; i < NE; i++) {
                    int off = sh + 2 * i;
                    e[i] = (int)alignpair((unsigned)d[off / 4 + 1], (unsigned)d[off / 4], (off & 3) * 8);
                }
#pragma unroll
                for (int co = 0; co < COUT; co++) {
#pragma unroll
                    for (int j = 0; j < KW; j++) {
                        int wv;
                        if constexpr (IN_FLOAT) wv = lwq[(co * CIN + ci) * KW + j];
                        else                    wv = wqi[(co * CIN + ci) * KW + j];
#pragma unroll
                        for (int p = 0; p < P; p++)
                            acc[co][p] = dot4(e[p + 2 * j], wv, acc[co][p]);
                    }
                }
            }

            const size_t ob = (size_t)(r0 + r) * COUT * LOUTP + l0;
#pragma unroll
            for (int co = 0; co < COUT; co++) {
                if (pact == P) {
                    short tmp[P];
#pragma unroll
                    for (int p = 0; p < P; p++) {
                        tmp[p] = (short)acc[co][p];
                        float v = (float)acc[co][p] * 0.015625f;
                        tsum[co] += v;
                        tsq[co]   = fmaf(v, v, tsq[co]);
                    }
                    short* op = &out[ob + (size_t)co * LOUTP];
                    if constexpr (P == 1) {
                        op[0] = tmp[0];
                    } else if constexpr (P == 2) {
                        *(short2*)op = make_short2(tmp[0], tmp[1]);
                    } else if constexpr (P == 4) {
                        *(short4*)op = make_short4(tmp[0], tmp[1], tmp[2], tmp[3]);
                    } else if constexpr (P == 8) {
                        *(short4*)op       = make_short4(tmp[0], tmp[1], tmp[2], tmp[3]);
                        *(short4*)(op + 4) = make_short4(tmp[4], tmp[5], tmp[6], tmp[7]);
                    }
                } else {
#pragma unroll
                    for (int p = 0; p < P; p++) {
                        if (p < pact) {
                            int k = acc[co][p];
                            out[ob + (size_t)co * LOUTP + p] = (short)k;
                            float v = (float)k * 0.015625f;
                            tsum[co] += v;
                            tsq[co]   = fmaf(v, v, tsq[co]);
                        }
                    }
                }
            }
        }

        // ---- per-vb fp32 stat reduction -> one fp64 atomic per channel ----
#pragma unroll
        for (int co = 0; co < COUT; co++) {
            float s = tsum[co], q = tsq[co];
            for (int off = 32; off > 0; off >>= 1) {
                s += __shfl_down(s, off, 64);
                q += __shfl_down(q, off, 64);
            }
            if (lane == 0) { red[wid * 2 * COUT + 2 * co] = s; red[wid * 2 * COUT + 2 * co + 1] = q; }
        }
        __syncthreads();
        if (tid < 2 * COUT) {
            float v = red[tid] + red[2 * COUT + tid] + red[4 * COUT + tid] + red[6 * COUT + tid];
            atomicAdd(&statsOut[(size_t)(vb & (NSLOT - 1)) * (2 * COUT) + tid], (double)v);
        }
        __syncthreads();   // protect smem + red for next vb
    }
}

// ---------------------------------------------------------------------------
// FC1 phase: rows strided by gridDim.x*4, one row per wave per iteration.
// r < B is block-uniform for any grid (B, stride multiples of 4; wid < 4).
// Partial grouping (4 rows/block-iter) + slot (bid&63) match the passing run.
// ---------------------------------------------------------------------------
DEV void fc1_phase(char* SB, const short* __restrict__ y5, const float* __restrict__ fw1,
                   const double* __restrict__ statsIn,
                   const float* __restrict__ g5, const float* __restrict__ b5,
                   float* __restrict__ z1, double* __restrict__ statsOut, int B)
{
    float* wq  = (float*)SB;               // 7400 floats
    float* ts  = (float*)(SB + 29600);
    float* tb  = (float*)(SB + 29696);
    float* red = (float*)(SB + 29792);     // [4][20]

    const int tid = threadIdx.x, bid = blockIdx.x;
    const int lane = tid & 63, wid = tid >> 6;

    for (int i = tid; i < 7400; i += 256) wq[i] = qwt(fw1[i]);
    for (int c = wid; c < 20; c += 4) {
        double S = statsIn[lane * 40 + 2 * c];
        double Q = statsIn[lane * 40 + 2 * c + 1];
        for (int off = 32; off > 0; off >>= 1) {
            S += shfl_down_d(S, off);
            Q += shfl_down_d(Q, off);
        }
        if (lane == 0) {
            double N = 8192.0 * 37.0;
            double mean = S / N;
            double var  = Q / N - mean * mean;
            double inv  = 1.0 / sqrt(var + 1e-5);
            double sc   = (double)g5[c] * inv;
            ts[c] = (float)sc;              // x already carries 1/64
            tb[c] = (float)((double)b5[c] - mean * sc);
        }
    }
    __syncthreads();

#pragma unroll 1
    for (int r = bid * 4 + wid; r < B; r += gridDim.x * 4) {
        const short* xr = y5 + (size_t)r * 800;   // 20ch x 40 padded
        float acc[10];
#pragma unroll
        for (int j = 0; j < 10; j++) acc[j] = 0.f;
#pragma unroll 1
        for (int f = lane; f < 740; f += 64) {
            int c = f / 37, pos = f - c * 37;
            float x = qact((float)xr[c * 40 + pos] * 0.015625f, ts[c], tb[c]);
#pragma unroll
            for (int j = 0; j < 10; j++) acc[j] = fmaf(x, wq[j * 740 + f], acc[j]);
        }
#pragma unroll
        for (int j = 0; j < 10; j++) {
            float v = acc[j];
            for (int off = 1; off < 64; off <<= 1) v += __shfl_xor(v, off, 64);
            if (lane == j) z1[(size_t)r * 10 + j] = v;
            if (lane == 0) { red[wid * 20 + 2 * j] = v; red[wid * 20 + 2 * j + 1] = v * v; }
        }
        __syncthreads();
        if (tid < 20) {
            float v = red[tid] + red[20 + tid] + red[40 + tid] + red[60 + tid];
            atomicAdd(&statsOut[(size_t)(bid & (NSLOT - 1)) * 20 + tid], (double)v);
        }
        __syncthreads();
    }
}

// ---------------------------------------------------------------------------
// FC2 part A: bridge(fc1 slots) -> z2 (global ws) + f64 stats -> sl7.
// Row loop strided by grid; single reduction + atomic per block after loop
// (blocks with no rows contribute exact zeros).
// ---------------------------------------------------------------------------
DEV void fc2a_phase(char* SB, const float* __restrict__ z1, const float* __restrict__ fw2,
                    const double* __restrict__ statsIn,
                    const float* __restrict__ g6, const float* __restrict__ b6,
                    float* __restrict__ z2, double* __restrict__ sl7, int B)
{
    float*  ts7 = (float*)SB;
    float*  tb7 = (float*)(SB + 64);
    float*  wq2 = (float*)(SB + 128);
    double* frd = (double*)(SB + 256);     // [4][4]

    const int tid = threadIdx.x, bid = blockIdx.x;
    const int lane = tid & 63, wid = tid >> 6;

    if (tid < 20) wq2[tid] = qwt(fw2[tid]);
    for (int c = wid; c < 10; c += 4) {
        double S = statsIn[lane * 20 + 2 * c];
        double Q = statsIn[lane * 20 + 2 * c + 1];
        for (int off = 32; off > 0; off >>= 1) {
            S += shfl_down_d(S, off);
            Q += shfl_down_d(Q, off);
        }
        if (lane == 0) {
            double N = 8192.0;
            double mean = S / N;
            double var  = Q / N - mean * mean;
            double inv  = 1.0 / sqrt(var + 1e-5);
            double sc   = (double)g6[c] * inv;
            ts7[c] = (float)sc;
            tb7[c] = (float)((double)b6[c] - mean * sc);
        }
    }
    __syncthreads();

    double s0 = 0.0, q0 = 0.0, s1 = 0.0, q1 = 0.0;
#pragma unroll 1
    for (int gt0 = bid * 256; gt0 < B; gt0 += gridDim.x * 256) {
        int gt = gt0 + tid;
        float a0 = 0.f, a1 = 0.f;
#pragma unroll
        for (int i = 0; i < 10; i++) {
            float x = qact(z1[(size_t)gt * 10 + i], ts7[i], tb7[i]);
            a0 = fmaf(x, wq2[i], a0);
            a1 = fmaf(x, wq2[10 + i], a1);
        }
        z2[2 * gt]     = a0;
        z2[2 * gt + 1] = a1;
        s0 += (double)a0; q0 += (double)a0 * (double)a0;
        s1 += (double)a1; q1 += (double)a1 * (double)a1;
    }
    for (int off = 32; off > 0; off >>= 1) {
        s0 += shfl_down_d(s0, off); q0 += shfl_down_d(q0, off);
        s1 += shfl_down_d(s1, off); q1 += shfl_down_d(q1, off);
    }
    if (lane == 0) { frd[wid * 4 + 0] = s0; frd[wid * 4 + 1] = q0; frd[wid * 4 + 2] = s1; frd[wid * 4 + 3] = q1; }
    __syncthreads();
    if (tid < 4) {
        double v = frd[tid] + frd[4 + tid] + frd[8 + tid] + frd[12 + tid];
        atomicAdd(&sl7[(size_t)(bid & (NSLOT - 1)) * 4 + tid], v);
    }
}

// FC2 part B: fold sl7 -> final BN apply.
DEV void fc2b_phase(char* SB, const float* __restrict__ z2, const double* __restrict__ sl7,
                    const float* __restrict__ g7, const float* __restrict__ b7,
                    float* __restrict__ outp, int B)
{
    float* tr = (float*)(SB + 512);        // [4] : sc0, sc1, bias0, bias1

    const int tid = threadIdx.x, bid = blockIdx.x;
    const int lane = tid & 63, wid = tid >> 6;

    for (int c = wid; c < 2; c += 4) {
        double S = sl7[lane * 4 + 2 * c];
        double Q = sl7[lane * 4 + 2 * c + 1];
        for (int off = 32; off > 0; off >>= 1) {
            S += shfl_down_d(S, off);
            Q += shfl_down_d(Q, off);
        }
        if (lane == 0) {
            double N = 8192.0;
            double mean = S / N;
            double var  = Q / N - mean * mean;
            double inv  = 1.0 / sqrt(var + 1e-5);
            double sc   = (double)g7[c] * inv;
            tr[c]     = (float)sc;
            tr[2 + c] = (float)((double)b7[c] - mean * sc);
        }
    }
    __syncthreads();
#pragma unroll 1
    for (int gt0 = bid * 256; gt0 < B; gt0 += gridDim.x * 256) {
        int gt = gt0 + tid;
        outp[2 * gt]     = fmaf(z2[2 * gt],     tr[0], tr[2]);
        outp[2 * gt + 1] = fmaf(z2[2 * gt + 1], tr[1], tr[3]);
    }
}

// ---------------------------------------------------------------------------
// Phase sequence shared by coop and fallback paths.
DEV void run_conv1(char* SB, const Params& p) {
    conv_phase<1, 3, 6, 1252, 623, 624, 8, 3, true, 1250>(SB,
        p.x, nullptr, nullptr, nullptr, nullptr, 0.0,
        p.y1, p.sl1, 8192, 2731, p.w1,
        p.w2, p.w3, p.w4, p.w5, p.wp2, p.wp3, p.wp4, p.wp5);
}
DEV void run_conv2(char* SB, const Params& p) {
    conv_phase<3, 5, 5, 624, 310, 312, 4, 4, false, 0>(SB,
        p.y1, p.wp2, p.sl1, p.g1, p.b1, 8192.0 * 623.0,
        p.y2, p.sl2, 8192, 2048, nullptr,
        nullptr, nullptr, nullptr, nullptr, nullptr, nullptr, nullptr, nullptr);
}
DEV void run_conv3(char* SB, const Params& p) {
    conv_phase<5, 10, 4, 312, 154, 160, 2, 4, false, 0>(SB,
        p.y2, p.wp3, p.sl2, p.g2, p.b2, 8192.0 * 310.0,
        p.y3, p.sl3, 8192, 2048, nullptr,
        nullptr, nullptr, nullptr, nullptr, nullptr, nullptr, nullptr, nullptr);
}
DEV void run_conv4(char* SB, const Params& p) {
    conv_phase<10, 20, 4, 160, 76, 80, 1, 4, false, 0>(SB,
        p.y3, p.wp4, p.sl3, p.g3, p.b3, 8192.0 * 154.0,
        p.y4, p.sl4, 8192, 2048, nullptr,
        nullptr, nullptr, nullptr, nullptr, nullptr, nullptr, nullptr, nullptr);
}
DEV void run_conv5(char* SB, const Params& p) {
    conv_phase<20, 20, 4, 80, 37, 40, 1, 8, false, 0>(SB,
        p.y4, p.wp5, p.sl4, p.g4, p.b4, 8192.0 * 76.0,
        p.y5, p.sl5, 8192, 1024, nullptr,
        nullptr, nullptr, nullptr, nullptr, nullptr, nullptr, nullptr, nullptr);
}

// Single cooperative kernel: all phases, grid sync at BN boundaries.
__global__ __launch_bounds__(256, 4) void fused_k(Params p)
{
    __shared__ double SBd[3840];           // 30720 B, reused per phase
    char* SB = (char*)SBd;
    cg::grid_group grid = cg::this_grid();

    run_conv1(SB, p); __threadfence(); grid.sync();
    run_conv2(SB, p); __threadfence(); grid.sync();
    run_conv3(SB, p); __threadfence(); grid.sync();
    run_conv4(SB, p); __threadfence(); grid.sync();
    run_conv5(SB, p); __threadfence(); grid.sync();
    fc1_phase(SB, p.y5, p.fw1, p.sl5, p.g5, p.b5, p.z1, p.sl6, 8192);
    __threadfence(); grid.sync();
    fc2a_phase(SB, p.z1, p.fw2, p.sl6, p.g6, p.b6, p.z2, p.sl7, 8192);
    __threadfence(); grid.sync();
    fc2b_phase(SB, p.z2, p.sl7, p.g7, p.b7, p.outp, 8192);
}

// Fallback: sequential per-phase kernels (kernel-boundary = global sync).
#define PHASE_WRAP(NAME, BODY) \
__global__ __launch_bounds__(256, 4) void NAME(Params p) { \
    __shared__ double SBd[3840]; char* SB = (char*)SBd; BODY; }

PHASE_WRAP(k_c1, run_conv1(SB, p))
PHASE_WRAP(k_c2, run_conv2(SB, p))
PHASE_WRAP(k_c3, run_conv3(SB, p))
PHASE_WRAP(k_c4, run_conv4(SB, p))
PHASE_WRAP(k_c5, run_conv5(SB, p))
PHASE_WRAP(k_f1, fc1_phase(SB, p.y5, p.fw1, p.sl5, p.g5, p.b5, p.z1, p.sl6, 8192))
PHASE_WRAP(k_f2a, fc2a_phase(SB, p.z1, p.fw2, p.sl6, p.g6, p.b6, p.z2, p.sl7, 8192))
PHASE_WRAP(k_f2b, fc2b_phase(SB, p.z2, p.sl7, p.g7, p.b7, p.outp, 8192))

// ---------------------------------------------------------------------------
extern "C" void kernel_launch(void* const* d_in, const int* in_sizes, int n_in,
                              void* d_out, int out_size, void* d_ws, size_t ws_size,
                              hipStream_t stream)
{
    (void)in_sizes; (void)n_in; (void)out_size; (void)ws_size;

    const float* x   = (const float*)d_in[0];
    const float* w1  = (const float*)d_in[1];
    const float* w2  = (const float*)d_in[2];
    const float* w3  = (const float*)d_in[3];
    const float* w4  = (const float*)d_in[4];
    const float* w5  = (const float*)d_in[5];
    const float* fw1 = (const float*)d_in[6];
    const float* fw2 = (const float*)d_in[7];
    const float *g[7], *bb[7];
    for (int i = 0; i < 7; i++) { g[i] = (const float*)d_in[8 + 2 * i]; bb[i] = (const float*)d_in[9 + 2 * i]; }

    char* ws = (char*)d_ws;
    size_t off = 0;
    auto alloc = [&](size_t bytes) -> void* {
        void* q = ws + off;
        off += (bytes + 255) & ~(size_t)255;
        return q;
    };
    short* y1 = (short*)alloc((size_t)8192 * 3 * 624 * 2);
    short* y2 = (short*)alloc((size_t)8192 * 5 * 312 * 2);
    short* y3 = (short*)alloc((size_t)8192 * 10 * 160 * 2);
    short* y4 = (short*)alloc((size_t)8192 * 20 * 80 * 2);
    short* y5 = (short*)alloc((size_t)8192 * 20 * 40 * 2);
    float* z1 = (float*)alloc((size_t)81920 * 4);
    float* z2 = (float*)alloc((size_t)8192 * 2 * 4);
    int*   wp2 = (int*)alloc(256);  int* wp3 = (int*)alloc(256);
    int*   wp4 = (int*)alloc(1024); int* wp5 = (int*)alloc(2048);
    // fp64 stat slots: NSLOT rows per layer; doubles = NSLOT*(6+10+20+40+40+20+4)
    double* slots = (double*)alloc((size_t)140 * NSLOT * 8);
    double* sl1 = slots;                  // conv1: NSLOT x 6
    double* sl2 = sl1 + NSLOT * 6;        // conv2: NSLOT x 10
    double* sl3 = sl2 + NSLOT * 10;       // conv3: NSLOT x 20
    double* sl4 = sl3 + NSLOT * 20;       // conv4: NSLOT x 40
    double* sl5 = sl4 + NSLOT * 40;       // conv5: NSLOT x 40
    double* sl6 = sl5 + NSLOT * 40;       // fc1:   NSLOT x 20
    double* sl7 = sl6 + NSLOT * 20;       // fc2:   NSLOT x 4

    hipMemsetAsync(slots, 0, (size_t)140 * NSLOT * 8, stream);

    Params hp;
    hp.x = x; hp.w1 = w1; hp.w2 = w2; hp.w3 = w3; hp.w4 = w4; hp.w5 = w5;
    hp.fw1 = fw1; hp.fw2 = fw2;
    hp.g1 = g[0]; hp.b1 = bb[0]; hp.g2 = g[1]; hp.b2 = bb[1];
    hp.g3 = g[2]; hp.b3 = bb[2]; hp.g4 = g[3]; hp.b4 = bb[3];
    hp.g5 = g[4]; hp.b5 = bb[4]; hp.g6 = g[5]; hp.b6 = bb[5];
    hp.g7 = g[6]; hp.b7 = bb[6];
    hp.y1 = y1; hp.y2 = y2; hp.y3 = y3; hp.y4 = y4; hp.y5 = y5;
    hp.z1 = z1; hp.z2 = z2;
    hp.wp2 = wp2; hp.wp3 = wp3; hp.wp4 = wp4; hp.wp5 = wp5;
    hp.sl1 = sl1; hp.sl2 = sl2; hp.sl3 = sl3; hp.sl4 = sl4;
    hp.sl5 = sl5; hp.sl6 = sl6; hp.sl7 = sl7;
    hp.outp = (float*)d_out;

    void* args[] = { &hp };
    hipError_t e = hipLaunchCooperativeKernel((const void*)fused_k, dim3(1024),
                                              dim3(256), args, 0u, stream);
    if (e != hipSuccess) {
        (void)hipGetLastError();
        e = hipLaunchCooperativeKernel((const void*)fused_k, dim3(512),
                                       dim3(256), args, 0u, stream);
    }
    if (e != hipSuccess) {
        (void)hipGetLastError();
        k_c1<<<2731, 256, 0, stream>>>(hp);
        k_c2<<<2048, 256, 0, stream>>>(hp);
        k_c3<<<2048, 256, 0, stream>>>(hp);
        k_c4<<<2048, 256, 0, stream>>>(hp);
        k_c5<<<1024, 256, 0, stream>>>(hp);
        k_f1<<<2048, 256, 0, stream>>>(hp);
        k_f2a<<<32, 256, 0, stream>>>(hp);
        k_f2b<<<32, 256, 0, stream>>>(hp);
    }
}

// Round 4
// 292.318 us; speedup vs baseline: 7.4984x; 7.4984x over previous
//
#include <hip/hip_runtime.h>

#define DEV __device__ __forceinline__

// ---- quantizer helpers (exact, round-half-even matches jnp.round) ----
DEV float qwt(float w) {
    float y = fminf(fmaxf(w, -1.0f), 0.875f);
    return rintf(y * 8.0f) * 0.125f;
}
DEV int qw8i(float w) {                       // weight -> int in [-8,7]
    float y = fminf(fmaxf(w, -1.0f), 0.875f);
    return (int)rintf(y * 8.0f);
}
DEV int q8i(float x, float a, float b) {      // act -> int in [-8,7]
    float y = fmaf(x, a, b);
    y = fminf(fmaxf(y, -1.0f), 0.875f);
    return (int)rintf(y * 8.0f);
}
DEV float qact(float x, float a, float b) {
    float y = fmaf(x, a, b);
    y = fminf(fmaxf(y, -1.0f), 0.875f);
    return rintf(y * 8.0f) * 0.125f;
}

DEV int dot4(int a, int b, int c) {
#if __has_builtin(__builtin_amdgcn_sdot4)
    return __builtin_amdgcn_sdot4(a, b, c, false);
#else
    c += (int)(signed char)(a)       * (int)(signed char)(b);
    c += (int)(signed char)(a >> 8)  * (int)(signed char)(b >> 8);
    c += (int)(signed char)(a >> 16) * (int)(signed char)(b >> 16);
    c += (int)(signed char)(a >> 24) * (int)(signed char)(b >> 24);
    return c;
#endif
}
DEV unsigned alignpair(unsigned hi, unsigned lo, int bits) {
#if __has_builtin(__builtin_amdgcn_alignbit)
    return __builtin_amdgcn_alignbit(hi, lo, bits);
#else
    return bits ? ((lo >> bits) | (hi << (32 - bits))) : lo;
#endif
}

// f64 atomic add (device scope; safe path)
DEV void atomAddF64(double* p, double v) {
    atomicAdd(p, v);
}

// pack float OIHW weights -> int8x4 dwords (value*8), zero-padded past K
DEV void pack_layer(const float* w, int* o, int CIN, int COUT, int K, int t) {
    int KW = (K + 3) / 4;
    for (int i = t; i < COUT * CIN * KW; i += 256) {
        int j = i % KW, cc = i / KW;
        unsigned r = 0;
        for (int u = 0; u < 4; u++) {
            int k = 4 * j + u;
            int b = (k < K) ? (qw8i(w[cc * K + k]) & 0xff) : 0;
            r |= (unsigned)b << (8 * u);
        }
        o[i] = (int)r;
    }
}

// ---------------------------------------------------------------------------
// int8/dot4 1-D strided conv (stride 2, VALID). R0-proven compute core and
// stat path (8 fp64 slot rows, serial 16-load bridge). NEW vs R0: virtual-
// block loop (vb = bid, bid+grid, ... < VB) so conv grids can be 1024 with
// 2-3 tiles per block — halves the workgroup launch ramp/drain. Stats are
// emitted per-vb with slot (vb & 7): identical multiset per slot as R0's
// one-block-per-vb version, and all f64 adds of f32 partials are exact
// (24-bit mantissas, small exponent spread) -> order-independent -> outputs
// bit-identical to the 293.6 us baseline.
// ---------------------------------------------------------------------------
template<int CIN,int COUT,int K,int LINP,int LOUT,int LOUTP,int P,int R,bool IN_FLOAT,int LIN=0>
__global__ __launch_bounds__(256) void conv_k(
    const void* __restrict__ in_, const int* __restrict__ wqi,
    const double* __restrict__ statsIn,
    const float* __restrict__ gprev, const float* __restrict__ bprev, double Nprev,
    short* __restrict__ out, double* __restrict__ statsOut, int B, int VB,
    const float* __restrict__ wown,
    const float* __restrict__ pw2, const float* __restrict__ pw3,
    const float* __restrict__ pw4, const float* __restrict__ pw5,
    int* __restrict__ owp2, int* __restrict__ owp3,
    int* __restrict__ owp4, int* __restrict__ owp5)
{
    constexpr int KW   = (K + 3) / 4;
    constexpr int NE   = P + 2 * KW - 1;
    constexpr int ND   = (2 * (NE - 1) + 3) / 4 + 2;
    constexpr int LO_P = (LOUT + P - 1) / P;
    constexpr int GROUPS = R * LO_P;

    __shared__ __align__(16) signed char smem[R * CIN * LINP + 32];
    __shared__ float ts[CIN], tb[CIN];
    __shared__ float red[4][2 * COUT];
    __shared__ int lwq[IN_FLOAT ? (COUT * CIN * KW) : 1];

    const int tid = threadIdx.x;
    const int bid = blockIdx.x;
    const int lane = tid & 63, wid = tid >> 6;

    if constexpr (IN_FLOAT) {
        for (int i = tid; i < COUT * CIN * KW; i += 256) {
            int j = i % KW, cc = i / KW;
            unsigned rr = 0;
            for (int u = 0; u < 4; u++) {
                int k = 4 * j + u;
                int bv = (k < K) ? (qw8i(wown[cc * K + k]) & 0xff) : 0;
                rr |= (unsigned)bv << (8 * u);
            }
            lwq[i] = (int)rr;
        }
        if (bid == 0) {
            pack_layer(pw2, owp2, 3, 5, 5, tid);
            pack_layer(pw3, owp3, 5, 10, 4, tid);
            pack_layer(pw4, owp4, 10, 20, 4, tid);
            pack_layer(pw5, owp5, 20, 20, 4, tid);
        }
    } else {
        // trivial BN bridge: 16 fp64 loads + fold, CIN threads (R0-proven)
        if (tid < CIN) {
            double S = 0.0, Q = 0.0;
#pragma unroll
            for (int s = 0; s < 8; s++) {
                S += statsIn[s * (2 * CIN) + 2 * tid];
                Q += statsIn[s * (2 * CIN) + 2 * tid + 1];
            }
            double mean = S / Nprev;
            double var  = Q / Nprev - mean * mean;
            double inv  = 1.0 / sqrt(var + 1e-5);
            double sc   = (double)gprev[tid] * inv;
            ts[tid] = (float)sc * 0.015625f;     // fold /64 of int16 storage
            tb[tid] = (float)((double)bprev[tid] - mean * sc);
        }
    }
    __syncthreads();

#pragma unroll 1
    for (int vb = bid; vb < VB; vb += gridDim.x) {
        const int r0   = vb * R;
        const int rcnt = min(R, B - r0);

        // ---- stage: global -> quantized int8 LDS ----
        if constexpr (IN_FLOAT) {
            constexpr int CH = LIN / 2;
            const float2* gp = (const float2*)in_;
            for (int c = tid; c < rcnt * CH; c += 256) {
                int r = c / CH, rem = c - r * CH;
                float2 v = gp[(size_t)(r0 + r) * CH + rem];
                int b0 = q8i(v.x, 1.f, 0.f) & 0xff;
                int b1 = q8i(v.y, 1.f, 0.f) & 0xff;
                *(unsigned short*)(smem + r * LINP + rem * 2) =
                    (unsigned short)(b0 | (b1 << 8));
            }
        } else {
            constexpr int CH  = CIN * LINP / 8;
            constexpr int CHC = LINP / 8;
            const int4* gp = (const int4*)((const short*)in_ + (size_t)r0 * CIN * LINP);
            for (int c = tid; c < rcnt * CH; c += 256) {
                int rem = c % CH;
                int ci = rem / CHC;
                float a = ts[ci], bo = tb[ci];
                int4 v = gp[c];
                int vs[4] = { v.x, v.y, v.z, v.w };
                unsigned pk[2];
#pragma unroll
                for (int u = 0; u < 2; u++) {
                    unsigned pp = 0;
#pragma unroll
                    for (int j = 0; j < 2; j++) {
                        int word = vs[u * 2 + j];
                        int b0 = q8i((float)(short)(word & 0xffff), a, bo) & 0xff;
                        int b1 = q8i((float)(short)(word >> 16),    a, bo) & 0xff;
                        pp |= (unsigned)(b0 | (b1 << 8)) << (16 * j);
                    }
                    pk[u] = pp;
                }
                ((uint2*)smem)[c] = make_uint2(pk[0], pk[1]);
            }
        }
        __syncthreads();

        float tsum[COUT], tsq[COUT];
#pragma unroll
        for (int c = 0; c < COUT; c++) { tsum[c] = 0.f; tsq[c] = 0.f; }

        // ---- compute core (R0 verbatim) ----
#pragma unroll 1
        for (int g = tid; g < GROUPS; g += 256) {
            int r = g / LO_P;
            if (r >= rcnt) continue;
            int l0   = (g - r * LO_P) * P;
            int pact = min(P, LOUT - l0);

            int acc[COUT][P];
#pragma unroll
            for (int co = 0; co < COUT; co++)
#pragma unroll
                for (int p = 0; p < P; p++) acc[co][p] = 0;

            const int ibase = r * CIN * LINP + 2 * l0;
            const int sh    = (P % 2 == 0) ? 0 : (ibase & 3);

            for (int ci = 0; ci < CIN; ci++) {
                const int* sp = (const int*)smem + ((ci * LINP + (ibase & ~3)) >> 2);
                int d[ND];
#pragma unroll
                for (int j = 0; j < ND; j++) d[j] = sp[j];
                int e[NE];
#pragma unroll
                for (int i = 0; i < NE; i++) {
                    int off = sh + 2 * i;
                    e[i] = (int)alignpair((unsigned)d[off / 4 + 1], (unsigned)d[off / 4], (off & 3) * 8);
                }
#pragma unroll
                for (int co = 0; co < COUT; co++) {
#pragma unroll
                    for (int j = 0; j < KW; j++) {
                        int wv;
                        if constexpr (IN_FLOAT) wv = lwq[(co * CIN + ci) * KW + j];
                        else                    wv = wqi[(co * CIN + ci) * KW + j];
#pragma unroll
                        for (int p = 0; p < P; p++)
                            acc[co][p] = dot4(e[p + 2 * j], wv, acc[co][p]);
                    }
                }
            }

            const size_t ob = (size_t)(r0 + r) * COUT * LOUTP + l0;
#pragma unroll
            for (int co = 0; co < COUT; co++) {
                if (pact == P) {
                    short tmp[P];
#pragma unroll
                    for (int p = 0; p < P; p++) {
                        tmp[p] = (short)acc[co][p];
                        float v = (float)acc[co][p] * 0.015625f;
                        tsum[co] += v;
                        tsq[co]   = fmaf(v, v, tsq[co]);
                    }
                    short* op = &out[ob + (size_t)co * LOUTP];
                    if constexpr (P == 1) {
                        op[0] = tmp[0];
                    } else if constexpr (P == 2) {
                        *(short2*)op = make_short2(tmp[0], tmp[1]);
                    } else if constexpr (P == 4) {
                        *(short4*)op = make_short4(tmp[0], tmp[1], tmp[2], tmp[3]);
                    } else if constexpr (P == 8) {
                        *(short4*)op       = make_short4(tmp[0], tmp[1], tmp[2], tmp[3]);
                        *(short4*)(op + 4) = make_short4(tmp[4], tmp[5], tmp[6], tmp[7]);
                    }
                } else {
#pragma unroll
                    for (int p = 0; p < P; p++) {
                        if (p < pact) {
                            int k = acc[co][p];
                            out[ob + (size_t)co * LOUTP + p] = (short)k;
                            float v = (float)k * 0.015625f;
                            tsum[co] += v;
                            tsq[co]   = fmaf(v, v, tsq[co]);
                        }
                    }
                }
            }
        }

        // ---- per-vb fp32 stat reduction -> one fp64 atomic per channel ----
#pragma unroll
        for (int co = 0; co < COUT; co++) {
            float s = tsum[co], q = tsq[co];
            for (int off = 32; off > 0; off >>= 1) {
                s += __shfl_down(s, off, 64);
                q += __shfl_down(q, off, 64);
            }
            if (lane == 0) { red[wid][2 * co] = s; red[wid][2 * co + 1] = q; }
        }
        __syncthreads();
        if (tid < 2 * COUT) {
            float v = red[0][tid] + red[1][tid] + red[2][tid] + red[3][tid];
            atomAddF64(&statsOut[(size_t)(vb & 7) * (2 * COUT) + tid], (double)v);
        }
        __syncthreads();   // protect smem + red for next vb
    }
}

// ---------------------------------------------------------------------------
// FC1: (B,740)x(10,740)^T, one wave per row (grid 2048). R0 verbatim.
// ---------------------------------------------------------------------------
__global__ __launch_bounds__(256) void fc1_k(
    const short* __restrict__ y5, const float* __restrict__ fw1,
    const double* __restrict__ statsIn,
    const float* __restrict__ g5, const float* __restrict__ b5,
    float* __restrict__ z1, double* __restrict__ statsOut, int B)
{
    __shared__ float wq[7400];
    __shared__ float ts[20], tb[20];
    __shared__ float red[4][20];

    const int tid = threadIdx.x;
    const int bid = blockIdx.x;

    for (int i = tid; i < 7400; i += 256) wq[i] = qwt(fw1[i]);
    if (tid < 20) {
        double S = 0.0, Q = 0.0;
#pragma unroll
        for (int s = 0; s < 8; s++) {
            S += statsIn[s * 40 + 2 * tid];
            Q += statsIn[s * 40 + 2 * tid + 1];
        }
        double N = 8192.0 * 37.0;
        double mean = S / N;
        double var  = Q / N - mean * mean;
        double inv  = 1.0 / sqrt(var + 1e-5);
        double sc   = (double)g5[tid] * inv;
        ts[tid] = (float)sc;                 // x already carries 1/64
        tb[tid] = (float)((double)b5[tid] - mean * sc);
    }
    __syncthreads();

    const int lane = tid & 63, wid = tid >> 6;
    float tsum[10], tsq[10];
#pragma unroll
    for (int j = 0; j < 10; j++) { tsum[j] = 0.f; tsq[j] = 0.f; }

#pragma unroll 1
    for (int r = bid * 4 + wid; r < B; r += gridDim.x * 4) {
        const short* xr = y5 + (size_t)r * 800;   // 20ch x 40 padded
        float acc[10];
#pragma unroll
        for (int j = 0; j < 10; j++) acc[j] = 0.f;
#pragma unroll 1
        for (int f = lane; f < 740; f += 64) {
            int c = f / 37, pos = f - c * 37;
            float x = qact((float)xr[c * 40 + pos] * 0.015625f, ts[c], tb[c]);
#pragma unroll
            for (int j = 0; j < 10; j++) acc[j] = fmaf(x, wq[j * 740 + f], acc[j]);
        }
#pragma unroll
        for (int j = 0; j < 10; j++) {
            float v = acc[j];
            for (int off = 1; off < 64; off <<= 1) v += __shfl_xor(v, off, 64);
            tsum[j] += v; tsq[j] = fmaf(v, v, tsq[j]);
            if (lane == j) z1[(size_t)r * 10 + j] = v;
        }
    }
    if (lane == 0) {
#pragma unroll
        for (int j = 0; j < 10; j++) { red[wid][2 * j] = tsum[j]; red[wid][2 * j + 1] = tsq[j]; }
    }
    __syncthreads();
    if (tid < 20) {
        float v = red[0][tid] + red[1][tid] + red[2][tid] + red[3][tid];
        atomAddF64(&statsOut[(size_t)(bid & 7) * 20 + tid], (double)v);
    }
}

// ---------------------------------------------------------------------------
// FC2 fused single-block: R0 verbatim.
// ---------------------------------------------------------------------------
__global__ __launch_bounds__(256) void fc2_fused_k(
    const float* __restrict__ z1, const float* __restrict__ fw2,
    const double* __restrict__ statsIn,
    const float* __restrict__ g6, const float* __restrict__ b6,
    const float* __restrict__ g7, const float* __restrict__ b7,
    float* __restrict__ outp, int B)
{
    __shared__ float zbuf[16384];
    __shared__ float ts7[10], tb7[10], wq2[20];
    __shared__ float fr[4][4];
    __shared__ float tr8[4];

    const int tid = threadIdx.x;
    const int lane = tid & 63, wid = tid >> 6;

    if (tid < 20) wq2[tid] = qwt(fw2[tid]);
    if (tid < 10) {
        double S = 0.0, Q = 0.0;
#pragma unroll
        for (int s = 0; s < 8; s++) {
            S += statsIn[s * 20 + 2 * tid];
            Q += statsIn[s * 20 + 2 * tid + 1];
        }
        double N = 8192.0;
        double mean = S / N;
        double var  = Q / N - mean * mean;
        double inv  = 1.0 / sqrt(var + 1e-5);
        double sc   = (double)g6[tid] * inv;
        ts7[tid] = (float)sc;
        tb7[tid] = (float)((double)b6[tid] - mean * sc);
    }
    __syncthreads();

    float s0 = 0.f, q0 = 0.f, s1 = 0.f, q1 = 0.f;
#pragma unroll 1
    for (int r = tid; r < B; r += 256) {
        float a0 = 0.f, a1 = 0.f;
#pragma unroll
        for (int i = 0; i < 10; i++) {
            float x = qact(z1[(size_t)r * 10 + i], ts7[i], tb7[i]);
            a0 = fmaf(x, wq2[i], a0);
            a1 = fmaf(x, wq2[10 + i], a1);
        }
        zbuf[r * 2]     = a0;
        zbuf[r * 2 + 1] = a1;
        s0 += a0; q0 = fmaf(a0, a0, q0);
        s1 += a1; q1 = fmaf(a1, a1, q1);
    }
    for (int off = 32; off > 0; off >>= 1) {
        s0 += __shfl_down(s0, off, 64); q0 += __shfl_down(q0, off, 64);
        s1 += __shfl_down(s1, off, 64); q1 += __shfl_down(q1, off, 64);
    }
    if (lane == 0) { fr[wid][0] = s0; fr[wid][1] = q0; fr[wid][2] = s1; fr[wid][3] = q1; }
    __syncthreads();
    if (tid < 2) {
        double S = 0.0, Q = 0.0;
        for (int w = 0; w < 4; w++) { S += (double)fr[w][2 * tid]; Q += (double)fr[w][2 * tid + 1]; }
        double N = (double)B;
        double mean = S / N;
        double var  = Q / N - mean * mean;
        double inv  = 1.0 / sqrt(var + 1e-5);
        double sc   = (double)g7[tid] * inv;
        tr8[tid]     = (float)sc;
        tr8[2 + tid] = (float)((double)b7[tid] - mean * sc);
    }
    __syncthreads();
    for (int i = tid; i < 2 * B; i += 256) {
        int c = i & 1;
        outp[i] = fmaf(zbuf[i], tr8[c], tr8[2 + c]);
    }
}

// ---------------------------------------------------------------------------
extern "C" void kernel_launch(void* const* d_in, const int* in_sizes, int n_in,
                              void* d_out, int out_size, void* d_ws, size_t ws_size,
                              hipStream_t stream)
{
    const float* x   = (const float*)d_in[0];
    const float* w1  = (const float*)d_in[1];
    const float* w2  = (const float*)d_in[2];
    const float* w3  = (const float*)d_in[3];
    const float* w4  = (const float*)d_in[4];
    const float* w5  = (const float*)d_in[5];
    const float* fw1 = (const float*)d_in[6];
    const float* fw2 = (const float*)d_in[7];
    const float *g[7], *bb[7];
    for (int i = 0; i < 7; i++) { g[i] = (const float*)d_in[8 + 2 * i]; bb[i] = (const float*)d_in[9 + 2 * i]; }

    char* ws = (char*)d_ws;
    size_t off = 0;
    auto alloc = [&](size_t bytes) -> void* {
        void* q = ws + off;
        off += (bytes + 255) & ~(size_t)255;
        return q;
    };
    short* y1 = (short*)alloc((size_t)8192 * 3 * 624 * 2);
    short* y2 = (short*)alloc((size_t)8192 * 5 * 312 * 2);
    short* y3 = (short*)alloc((size_t)8192 * 10 * 160 * 2);
    short* y4 = (short*)alloc((size_t)8192 * 20 * 80 * 2);
    short* y5 = (short*)alloc((size_t)8192 * 20 * 40 * 2);
    float* z1 = (float*)alloc((size_t)81920 * 4);
    int*   wp2 = (int*)alloc(256);  int* wp3 = (int*)alloc(256);
    int*   wp4 = (int*)alloc(1024); int* wp5 = (int*)alloc(2048);
    // fp64 stat slots: 8 rows of 2C per layer, contiguous (1088 doubles)
    double* slots = (double*)alloc((size_t)1088 * 8);
    double* sl1 = slots;              // conv1: 8 x 6
    double* sl2 = sl1 + 8 * 6;        // conv2: 8 x 10
    double* sl3 = sl2 + 8 * 10;       // conv3: 8 x 20
    double* sl4 = sl3 + 8 * 20;       // conv4: 8 x 40
    double* sl5 = sl4 + 8 * 40;       // conv5: 8 x 40
    double* sl6 = sl5 + 8 * 40;       // fc1:   8 x 20

    const int B = 8192;

    hipMemsetAsync(slots, 0, (size_t)1088 * 8, stream);

    // conv1: (B,1,1250) f32 -> (B,3,624p); P=8, R=3, VB=2731, grid 1024
    conv_k<1, 3, 6, 1252, 623, 624, 8, 3, true, 1250><<<1024, 256, 0, stream>>>(
        x, nullptr, nullptr, nullptr, nullptr, 0.0, y1, sl1, B, 2731,
        w1, w2, w3, w4, w5, wp2, wp3, wp4, wp5);
    // conv2: P=4, R=4, VB=2048, grid 1024 (bridge BN1 from sl1)
    conv_k<3, 5, 5, 624, 310, 312, 4, 4, false><<<1024, 256, 0, stream>>>(
        y1, wp2, sl1, g[0], bb[0], 8192.0 * 623.0, y2, sl2, B, 2048,
        nullptr, nullptr, nullptr, nullptr, nullptr, nullptr, nullptr, nullptr, nullptr);
    // conv3: P=2, R=4, VB=2048, grid 1024
    conv_k<5, 10, 4, 312, 154, 160, 2, 4, false><<<1024, 256, 0, stream>>>(
        y2, wp3, sl2, g[1], bb[1], 8192.0 * 310.0, y3, sl3, B, 2048,
        nullptr, nullptr, nullptr, nullptr, nullptr, nullptr, nullptr, nullptr, nullptr);
    // conv4: P=1, R=4, VB=2048, grid 1024
    conv_k<10, 20, 4, 160, 76, 80, 1, 4, false><<<1024, 256, 0, stream>>>(
        y3, wp4, sl3, g[2], bb[2], 8192.0 * 154.0, y4, sl4, B, 2048,
        nullptr, nullptr, nullptr, nullptr, nullptr, nullptr, nullptr, nullptr, nullptr);
    // conv5: P=1, R=8, VB=1024, grid 1024
    conv_k<20, 20, 4, 80, 37, 40, 1, 8, false><<<1024, 256, 0, stream>>>(
        y4, wp5, sl4, g[3], bb[3], 8192.0 * 76.0, y5, sl5, B, 1024,
        nullptr, nullptr, nullptr, nullptr, nullptr, nullptr, nullptr, nullptr, nullptr);
    // fc1: grid 2048, one row per wave (bridge BN5 from sl5)
    fc1_k<<<2048, 256, 0, stream>>>(y5, fw1, sl5, g[4], bb[4], z1, sl6, B);
    // fc2 + bridge(fc1) + stats + apply, single block
    fc2_fused_k<<<1, 256, 0, stream>>>(z1, fw2, sl6, g[5], bb[5], g[6], bb[6],
                                       (float*)d_out, B);
}